// Round 1
// baseline (436.278 us; speedup 1.0000x reference)
//
#include <hip/hip_runtime.h>
#include <math.h>

#define N_NODES 30000
#define E_EDGES 480000
#define VD      512
#define HID     32

// ws layout (floats):
//   [0..8)          stats: S0,S1,S00,S11,S01 (atomic accum, zeroed)
//   [8 .. 8+N)      acc   (atomic accum, zeroed)
//   [8+N .. 8+2N)   deg   (atomic accum, zeroed)
//   [8+2N .. 8+3N)  inv   (written fully)
//   [8+3N .. 8+4N)  s     (written fully)

// ---------------- stats over x: 5 moments ----------------
__global__ void k_stats(const float* __restrict__ x, float* __restrict__ stats, int n) {
    float s0 = 0.f, s1 = 0.f, s00 = 0.f, s11 = 0.f, s01 = 0.f;
    for (int i = blockIdx.x * blockDim.x + threadIdx.x; i < n; i += gridDim.x * blockDim.x) {
        float2 v = ((const float2*)x)[i];
        s0  += v.x;       s1  += v.y;
        s00 += v.x * v.x; s11 += v.y * v.y;
        s01 += v.x * v.y;
    }
    // wave butterfly reduce (64 lanes)
    for (int o = 32; o; o >>= 1) {
        s0  += __shfl_xor(s0,  o, 64);
        s1  += __shfl_xor(s1,  o, 64);
        s00 += __shfl_xor(s00, o, 64);
        s11 += __shfl_xor(s11, o, 64);
        s01 += __shfl_xor(s01, o, 64);
    }
    if ((threadIdx.x & 63) == 0) {
        atomicAdd(&stats[0], s0);
        atomicAdd(&stats[1], s1);
        atomicAdd(&stats[2], s00);
        atomicAdd(&stats[3], s11);
        atomicAdd(&stats[4], s01);
    }
}

// ---------------- inverse norms of visual rows ----------------
__global__ void k_inv(const float* __restrict__ visual, float* __restrict__ inv, int n) {
    int wave  = (blockIdx.x * blockDim.x + threadIdx.x) >> 6;
    int lane  = threadIdx.x & 63;
    int nwave = (gridDim.x * blockDim.x) >> 6;
    for (int node = wave; node < n; node += nwave) {
        const float4* row = (const float4*)(visual + (size_t)node * VD);
        float4 a = row[lane];
        float4 b = row[lane + 64];
        float p = a.x*a.x + a.y*a.y + a.z*a.z + a.w*a.w
                + b.x*b.x + b.y*b.y + b.z*b.z + b.w*b.w;
        for (int o = 32; o; o >>= 1) p += __shfl_xor(p, o, 64);
        if (lane == 0) {
            float nm = sqrtf(p);
            inv[node] = 1.0f / fmaxf(nm, 1e-8f);
        }
    }
}

// ---------------- per-node scalar s[n] ----------------
__global__ void k_node(const float* __restrict__ x,
                       const float* __restrict__ w1, const float* __restrict__ b1,
                       const float* __restrict__ gamma, const float* __restrict__ beta,
                       const float* __restrict__ prelu_a,
                       const float* __restrict__ w2, const float* __restrict__ b2,
                       const float* __restrict__ wc, const float* __restrict__ wp,
                       const float* __restrict__ stats,
                       float* __restrict__ sarr, int n) {
    __shared__ float s_scale[HID], s_shift[HID], s_u[HID], s_w1a[HID], s_w1b[HID];
    __shared__ float s_wpc[HID];
    __shared__ float s_sb;
    int t = threadIdx.x;
    if (t < HID) {
        // wpc[k] = sum_j wp[j] * wc[j*HID + k]
        float wpck = 0.f;
        for (int j = 0; j < HID; ++j) wpck += wp[j] * wc[j * HID + t];
        s_wpc[t] = wpck;
        const float invN = 1.0f / (float)n;
        float m0  = stats[0] * invN, m1 = stats[1] * invN;
        float v0  = fmaxf(stats[2] * invN - m0 * m0, 0.f);
        float v1  = fmaxf(stats[3] * invN - m1 * m1, 0.f);
        float c01 = stats[4] * invN - m0 * m1;
        float a0 = w1[2 * t], a1 = w1[2 * t + 1];
        float mean = a0 * m0 + a1 * m1 + b1[t];
        float var  = fmaxf(a0 * a0 * v0 + a1 * a1 * v1 + 2.f * a0 * a1 * c01, 0.f);
        float rs    = 1.0f / sqrtf(var + 1e-5f);
        float scale = gamma[t] * rs;
        s_scale[t] = scale;
        s_shift[t] = beta[t] - mean * scale;
        s_w1a[t] = a0; s_w1b[t] = a1;
    }
    __syncthreads();
    if (t < HID) {
        // u[c] = sum_k wpc[k] * w2[k*HID + c]
        float uu = 0.f;
        for (int k = 0; k < HID; ++k) uu += s_wpc[k] * w2[k * HID + t];
        s_u[t] = uu;
    }
    if (t == 0) {
        float sb = 0.f;
        for (int k = 0; k < HID; ++k) sb += s_wpc[k] * b2[k];
        s_sb = sb;
    }
    __syncthreads();
    const float aslope = prelu_a[0];
    const float sb = s_sb;
    for (int i = blockIdx.x * blockDim.x + t; i < n; i += gridDim.x * blockDim.x) {
        float2 xv = ((const float2*)x)[i];
        float sacc = sb;
        #pragma unroll
        for (int c = 0; c < HID; ++c) {
            float h  = s_w1a[c] * xv.x + s_w1b[c] * xv.y + b1[c];
            float tt = h * s_scale[c] + s_shift[c];
            tt = tt >= 0.f ? tt : aslope * tt;
            sacc += tt * s_u[c];
        }
        sarr[i] = sacc;
    }
}

// ---------------- edge kernel: cosine + scalar scatter ----------------
__global__ void __launch_bounds__(256) k_edge(const int* __restrict__ ei,
                                              const float* __restrict__ visual,
                                              const float* __restrict__ inv,
                                              const float* __restrict__ sarr,
                                              float* __restrict__ acc,
                                              float* __restrict__ deg) {
    int wave  = (blockIdx.x * blockDim.x + threadIdx.x) >> 6;
    int lane  = threadIdx.x & 63;
    int nwave = (gridDim.x * blockDim.x) >> 6;
    for (int e = wave; e < E_EDGES; e += nwave) {
        int s = ei[e];
        int d = ei[E_EDGES + e];
        const float4* ra = (const float4*)(visual + (size_t)s * VD);
        const float4* rb = (const float4*)(visual + (size_t)d * VD);
        float4 a0 = ra[lane];
        float4 b0 = rb[lane];
        float4 a1 = ra[lane + 64];
        float4 b1 = rb[lane + 64];
        float p = a0.x*b0.x + a0.y*b0.y + a0.z*b0.z + a0.w*b0.w
                + a1.x*b1.x + a1.y*b1.y + a1.z*b1.z + a1.w*b1.w;
        for (int o = 32; o; o >>= 1) p += __shfl_xor(p, o, 64);
        if (lane == 0) {
            float w = p * inv[s] * inv[d];
            atomicAdd(&acc[d], w * sarr[s]);
            atomicAdd(&deg[d], 1.0f);
        }
    }
}

// ---------------- final: mean + affine const ----------------
__global__ void k_final(const float* __restrict__ acc, const float* __restrict__ deg,
                        const float* __restrict__ bc, const float* __restrict__ wp,
                        const float* __restrict__ bp, float* __restrict__ out, int n) {
    float K = bp[0];
    #pragma unroll
    for (int j = 0; j < HID; ++j) K += wp[j] * bc[j];
    for (int i = blockIdx.x * blockDim.x + threadIdx.x; i < n; i += gridDim.x * blockDim.x) {
        out[i] = acc[i] / fmaxf(deg[i], 1.0f) + K;
    }
}

extern "C" void kernel_launch(void* const* d_in, const int* in_sizes, int n_in,
                              void* d_out, int out_size, void* d_ws, size_t ws_size,
                              hipStream_t stream) {
    const float* x       = (const float*)d_in[0];
    const float* visual  = (const float*)d_in[1];
    const int*   ei      = (const int*)  d_in[2];
    const float* w1      = (const float*)d_in[3];
    const float* b1      = (const float*)d_in[4];
    const float* gamma   = (const float*)d_in[5];
    const float* beta    = (const float*)d_in[6];
    const float* prelu_a = (const float*)d_in[7];
    const float* w2      = (const float*)d_in[8];
    const float* b2      = (const float*)d_in[9];
    const float* wc      = (const float*)d_in[10];
    const float* bc      = (const float*)d_in[11];
    const float* wp      = (const float*)d_in[12];
    const float* bp      = (const float*)d_in[13];
    float* out = (float*)d_out;

    float* ws    = (float*)d_ws;
    float* stats = ws;
    float* acc   = ws + 8;
    float* deg   = ws + 8 + N_NODES;
    float* inv   = ws + 8 + 2 * N_NODES;
    float* sarr  = ws + 8 + 3 * N_NODES;

    // zero the atomic accumulators (stats + acc + deg)
    hipMemsetAsync(ws, 0, (size_t)(8 + 2 * N_NODES) * sizeof(float), stream);

    k_stats<<<128, 256, 0, stream>>>(x, stats, N_NODES);
    k_inv  <<<512, 256, 0, stream>>>(visual, inv, N_NODES);
    k_node <<<256, 256, 0, stream>>>(x, w1, b1, gamma, beta, prelu_a, w2, b2, wc, wp,
                                     stats, sarr, N_NODES);
    k_edge <<<4096, 256, 0, stream>>>(ei, visual, inv, sarr, acc, deg);
    k_final<<<128, 256, 0, stream>>>(acc, deg, bc, wp, bp, out, N_NODES);
}